// Round 11
// baseline (196.953 us; speedup 1.0000x reference)
//
#include <hip/hip_runtime.h>
#include <math.h>

using f32x4  = __attribute__((ext_vector_type(4))) float;
using bf16x8 = __attribute__((ext_vector_type(8))) short;

constexpr int kB = 4, kC = 256, kL = 2048, kH = 8;
constexpr float kQScale = 0.25505402264f;  // 1/sqrt(32) * log2(e)

__device__ __forceinline__ unsigned short f2bf(float f) {
    unsigned u = __builtin_bit_cast(unsigned, f);
    u += 0x7fffu + ((u >> 16) & 1u);
    return (unsigned short)(u >> 16);
}
__device__ __forceinline__ unsigned cvt_pk(float lo, float hi) {
    unsigned r;
    asm("v_cvt_pk_bf16_f32 %0, %1, %2" : "=v"(r) : "v"(lo), "v"(hi));
    return r;
}
__device__ __forceinline__ f32x4 mfma16(bf16x8 a, bf16x8 b, f32x4 c) {
    return __builtin_amdgcn_mfma_f32_16x16x32_bf16(a, b, c, 0, 0, 0);
}
__device__ __forceinline__ bf16x8 bc8(unsigned a, unsigned b, unsigned c, unsigned d) {
    return __builtin_bit_cast(bf16x8, make_uint4(a, b, c, d));
}

// ---------------------------------------------------------------------------
// Fused GN (blocks 0..127) + weight cvt (blocks 128..383): one launch stage.
// GN: one block per (b,group), outputs hT bf16 [B][L][C].
// CVT: fp32 -> bf16 for both weight matrices.
// ---------------------------------------------------------------------------
__global__ __launch_bounds__(256) void gncvt_kernel(const float* __restrict__ x,
                                                    const float* __restrict__ gw,
                                                    const float* __restrict__ gb,
                                                    unsigned short* __restrict__ hT,
                                                    const float* __restrict__ qkvw,
                                                    const float* __restrict__ outw,
                                                    unsigned short* __restrict__ wq,
                                                    unsigned short* __restrict__ wo) {
    if (blockIdx.x >= 128) {  // ---- cvt role ----
        int i = (blockIdx.x - 128) * 256 + threadIdx.x;  // 0..65535 float4s
        const float* s; unsigned short* d; int j;
        if (i < 49152) { s = qkvw; d = wq; j = i; }
        else           { s = outw; d = wo; j = i - 49152; }
        float4 v = ((const float4*)s)[j];
        ((uint2*)d)[j] = make_uint2(cvt_pk(v.x, v.y), cvt_pk(v.z, v.w));
        return;
    }
    // ---- groupnorm role ----
    int b = blockIdx.x >> 5, g = blockIdx.x & 31;
    int t = threadIdx.x;
    const float* xp = x + ((size_t)b * kC + g * 8) * kL + 8 * t;

    float v[8][8];
    float s = 0.f, ss = 0.f;
#pragma unroll
    for (int c = 0; c < 8; ++c) {
        float4 a  = *(const float4*)(xp + (size_t)c * kL);
        float4 a2 = *(const float4*)(xp + (size_t)c * kL + 4);
        v[c][0]=a.x; v[c][1]=a.y; v[c][2]=a.z; v[c][3]=a.w;
        v[c][4]=a2.x; v[c][5]=a2.y; v[c][6]=a2.z; v[c][7]=a2.w;
        s  += (a.x+a.y)+(a.z+a.w)+(a2.x+a2.y)+(a2.z+a2.w);
        ss += a.x*a.x+a.y*a.y+a.z*a.z+a.w*a.w+a2.x*a2.x+a2.y*a2.y+a2.z*a2.z+a2.w*a2.w;
    }
#pragma unroll
    for (int off = 32; off; off >>= 1) {
        s  += __shfl_down(s, off);
        ss += __shfl_down(ss, off);
    }
    __shared__ float red[8];
    int wv = t >> 6;
    if ((t & 63) == 0) { red[wv] = s; red[4 + wv] = ss; }
    __syncthreads();
    s  = red[0] + red[1] + red[2] + red[3];
    ss = red[4] + red[5] + red[6] + red[7];
    float mean = s * (1.f / 16384.f);
    float var  = ss * (1.f / 16384.f) - mean * mean;
    float rstd = rsqrtf(var + 1e-5f);

    float wc[8], bc[8];
#pragma unroll
    for (int c = 0; c < 8; ++c) { wc[c] = gw[g*8+c] * rstd; bc[c] = gb[g*8+c]; }

    unsigned short* hp = hT + ((size_t)b * kL + 8 * t) * kC + g * 8;
#pragma unroll
    for (int j = 0; j < 8; ++j) {
        unsigned pk[4];
#pragma unroll
        for (int c2 = 0; c2 < 4; ++c2) {
            pk[c2] = cvt_pk((v[2*c2  ][j] - mean) * wc[2*c2  ] + bc[2*c2  ],
                            (v[2*c2+1][j] - mean) * wc[2*c2+1] + bc[2*c2+1]);
        }
        *(uint4*)(hp + (size_t)j * kC) = make_uint4(pk[0], pk[1], pk[2], pk[3]);
    }
}

// ---------------------------------------------------------------------------
// Merged QKV GEMM, W-in-registers. Block: o-tile 64 (wave=16 rows), n-tile 128.
// q,k stored transposed [B][H][L][32]; v stored [B][256][L].
// q pre-scaled by 1/sqrt(D)*log2(e), bias fused.
// ---------------------------------------------------------------------------
__device__ __forceinline__ void store_qk(unsigned short* __restrict__ base, size_t bh,
                                         int n, int d0, f32x4 acc,
                                         const float* bias4, float scale) {
    float v0 = (acc[0] + bias4[0]) * scale, v1 = (acc[1] + bias4[1]) * scale;
    float v2 = (acc[2] + bias4[2]) * scale, v3 = (acc[3] + bias4[3]) * scale;
    *(uint2*)(base + (bh * kL + n) * 32 + d0) = make_uint2(cvt_pk(v0, v1), cvt_pk(v2, v3));
}

__global__ __launch_bounds__(256) void qkv_gemm(const unsigned short* __restrict__ Wb,
                                                const unsigned short* __restrict__ hT,
                                                const float* __restrict__ qkvb,
                                                unsigned short* __restrict__ qT,
                                                unsigned short* __restrict__ kT,
                                                unsigned short* __restrict__ vbuf) {
    int t = threadIdx.x, wv = t >> 6, ll = t & 15, lg = (t >> 4) & 3;
    int n0 = blockIdx.x * 128, o0 = blockIdx.y * 64, b = blockIdx.z;
    int obase = o0 + wv * 16;
    const unsigned short* hb = hT + (size_t)b * kL * kC;

    bf16x8 wf[8];
#pragma unroll
    for (int k = 0; k < 8; ++k)
        wf[k] = *(const bf16x8*)(Wb + (size_t)(obase + ll) * 256 + 32 * k + 8 * lg);
    float bias[4];
#pragma unroll
    for (int r = 0; r < 4; ++r) bias[r] = qkvb[obase + 4 * lg + r];
    int mode = (obase < 256) ? 0 : (obase < 512 ? 1 : 2);
    int d0 = (obase & 31) + 4 * lg;

    for (int np = 0; np < 4; ++np) {
        f32x4 acc0 = {}, acc1 = {};
        int nA = n0 + np * 32 + ll, nB = nA + 16;
#pragma unroll
        for (int k = 0; k < 8; ++k) {
            bf16x8 h0 = *(const bf16x8*)(hb + (size_t)nA * 256 + 32 * k + 8 * lg);
            bf16x8 h1 = *(const bf16x8*)(hb + (size_t)nB * 256 + 32 * k + 8 * lg);
            acc0 = mfma16(wf[k], h0, acc0);
            acc1 = mfma16(wf[k], h1, acc1);
        }
        if (mode == 0) {
            size_t bh = (size_t)b * kH + (obase >> 5);
            store_qk(qT, bh, nA, d0, acc0, bias, kQScale);
            store_qk(qT, bh, nB, d0, acc1, bias, kQScale);
        } else if (mode == 1) {
            size_t bh = (size_t)b * kH + ((obase - 256) >> 5);
            store_qk(kT, bh, nA, d0, acc0, bias, 1.f);
            store_qk(kT, bh, nB, d0, acc1, bias, 1.f);
        } else {
#pragma unroll
            for (int r = 0; r < 4; ++r) {
                size_t row = (size_t)b * kC + (obase - 512) + 4 * lg + r;
                vbuf[row * kL + nA] = f2bf(acc0[r] + bias[r]);
                vbuf[row * kL + nB] = f2bf(acc1[r] + bias[r]);
            }
        }
    }
}

// ---------------------------------------------------------------------------
// Flash attention v11: r10 numerics (fp32 lsum, same per-lane add order,
// no-max exp2) with the LDS P-transpose DELETED via lane-local P
// (validated accurate in r7 at absmax 0.03125 with this same fp32 path):
//   key(k-slot 8g+e) = m0 + 16*(e>>2) + 4*g + (e&3), V loaded to match.
// 16 q/wave -> 4096 waves = 4 waves/SIMD (2x r10's TLP, the binding limit).
// r4/r10 prefetch idiom (in-loop decls + end-of-loop copies + unroll 2).
// No LDS, no barriers, no cross-lane ops in the loop. Grid 4096, XCD-swizzled.
// ---------------------------------------------------------------------------
__global__ __launch_bounds__(64) void attn_kernel(const unsigned short* __restrict__ qT,
                                                  const unsigned short* __restrict__ kT,
                                                  const unsigned short* __restrict__ vbuf,
                                                  unsigned short* __restrict__ h2T) {
    int t = threadIdx.x, ll = t & 15, g = (t >> 4) & 3;
    int j = blockIdx.x;
    int bid = (j & 7) * 512 + (j >> 3);   // XCD swizzle: 4096 = 8 x 512, bijective
    int qt = bid & 127, bh = bid >> 7;    // qt 0..127 (16-q tiles), bh 0..31
    int b = bh >> 3, h = bh & 7;
    const unsigned short* kb = kT + (size_t)bh * kL * 32;
    const unsigned short* vb = vbuf + ((size_t)b * kC + h * 32) * kL;
    int nq = qt * 16;                     // queries nq..nq+15

    bf16x8 qf = *(const bf16x8*)(qT + (size_t)bh * kL * 32 + (size_t)(nq + ll) * 32 + 8 * g);

    f32x4 acc0 = {}, acc1 = {};
    float lsum = 0.f;
    const f32x4 zero = {0.f, 0.f, 0.f, 0.f};

    const int koff  = ll * 32 + 8 * g;          // K row=key, stride 32
    const int voff0 = ll * kL + 4 * g;          // V d=ll row
    const int voff1 = (16 + ll) * kL + 4 * g;   // V d=16+ll row

    // prefetch tile 0 (r4/r10 idiom)
    bf16x8 ka0 = *(const bf16x8*)(kb + koff);
    bf16x8 ka1 = *(const bf16x8*)(kb + 512 + koff);
    uint2  v00 = *(const uint2*)(vb + voff0);
    uint2  v01 = *(const uint2*)(vb + voff0 + 16);
    uint2  v10 = *(const uint2*)(vb + voff1);
    uint2  v11 = *(const uint2*)(vb + voff1 + 16);

#pragma unroll 2
    for (int m0 = 0; m0 < kL; m0 += 32) {
        int mn = (m0 + 32) & (kL - 1);    // next tile (wraps on last, unused)
        bf16x8 nka0 = *(const bf16x8*)(kb + mn * 32 + koff);
        bf16x8 nka1 = *(const bf16x8*)(kb + mn * 32 + 512 + koff);
        uint2  nv00 = *(const uint2*)(vb + voff0 + mn);
        uint2  nv01 = *(const uint2*)(vb + voff0 + mn + 16);
        uint2  nv10 = *(const uint2*)(vb + voff1 + mn);
        uint2  nv11 = *(const uint2*)(vb + voff1 + mn + 16);

        // QK^T (swapped): s0[r] = S[key m0+4g+r][query nq+ll], s1: +16
        __builtin_amdgcn_s_setprio(1);
        f32x4 s0 = mfma16(ka0, qf, zero);
        f32x4 s1 = mfma16(ka1, qf, zero);
        __builtin_amdgcn_s_setprio(0);

        // p = exp2(s); fp32 lane-local lsum in r10's exact add order
        float p0 = __builtin_amdgcn_exp2f(s0[0]);
        float p1 = __builtin_amdgcn_exp2f(s0[1]);
        float p2 = __builtin_amdgcn_exp2f(s0[2]);
        float p3 = __builtin_amdgcn_exp2f(s0[3]);
        lsum += (p0 + p1) + (p2 + p3);
        float p4 = __builtin_amdgcn_exp2f(s1[0]);
        float p5 = __builtin_amdgcn_exp2f(s1[1]);
        float p6 = __builtin_amdgcn_exp2f(s1[2]);
        float p7 = __builtin_amdgcn_exp2f(s1[3]);
        lsum += (p4 + p5) + (p6 + p7);

        bf16x8 pb = bc8(cvt_pk(p0, p1), cvt_pk(p2, p3),
                        cvt_pk(p4, p5), cvt_pk(p6, p7));
        bf16x8 va0 = bc8(v00.x, v00.y, v01.x, v01.y);
        bf16x8 va1 = bc8(v10.x, v10.y, v11.x, v11.y);

        __builtin_amdgcn_s_setprio(1);
        acc0 = mfma16(va0, pb, acc0);     // d = 4g+r
        acc1 = mfma16(va1, pb, acc1);     // d = 16+4g+r
        __builtin_amdgcn_s_setprio(0);

        ka0 = nka0; ka1 = nka1;
        v00 = nv00; v01 = nv01; v10 = nv10; v11 = nv11;
    }

    lsum += __shfl_xor(lsum, 16);
    lsum += __shfl_xor(lsum, 32);
    float inv = 1.f / lsum;
    unsigned short* ob = h2T + ((size_t)b * kL + nq + ll) * kC + h * 32;
    *(uint2*)(ob + 4 * g)      = make_uint2(cvt_pk(acc0[0] * inv, acc0[1] * inv),
                                            cvt_pk(acc0[2] * inv, acc0[3] * inv));
    *(uint2*)(ob + 16 + 4 * g) = make_uint2(cvt_pk(acc1[0] * inv, acc1[1] * inv),
                                            cvt_pk(acc1[2] * inv, acc1[3] * inv));
}

// ---------------------------------------------------------------------------
// OUT GEMM, W-in-registers. Block: o-tile 64 (wave=16), n-tile 64.
// out[o][n] = sum_c Wout[o][c] h2T[n][c] + bias + x, fp32 out.
// ---------------------------------------------------------------------------
__global__ __launch_bounds__(256) void out_gemm(const unsigned short* __restrict__ Wb,
                                                const unsigned short* __restrict__ h2T,
                                                const float* __restrict__ outb,
                                                const float* __restrict__ x,
                                                float* __restrict__ out) {
    int t = threadIdx.x, wv = t >> 6, ll = t & 15, lg = (t >> 4) & 3;
    int n0 = blockIdx.x * 64, o0 = blockIdx.y * 64, b = blockIdx.z;
    int obase = o0 + wv * 16;
    const unsigned short* hb = h2T + (size_t)b * kL * kC;

    bf16x8 wf[8];
#pragma unroll
    for (int k = 0; k < 8; ++k)
        wf[k] = *(const bf16x8*)(Wb + (size_t)(obase + ll) * 256 + 32 * k + 8 * lg);
    float bias[4];
#pragma unroll
    for (int r = 0; r < 4; ++r) bias[r] = outb[obase + 4 * lg + r];

    for (int np = 0; np < 2; ++np) {
        f32x4 acc0 = {}, acc1 = {};
        int nA = n0 + np * 32 + ll, nB = nA + 16;
#pragma unroll
        for (int k = 0; k < 8; ++k) {
            bf16x8 h0 = *(const bf16x8*)(hb + (size_t)nA * 256 + 32 * k + 8 * lg);
            bf16x8 h1 = *(const bf16x8*)(hb + (size_t)nB * 256 + 32 * k + 8 * lg);
            acc0 = mfma16(wf[k], h0, acc0);
            acc1 = mfma16(wf[k], h1, acc1);
        }
#pragma unroll
        for (int r = 0; r < 4; ++r) {
            size_t row = (size_t)b * kC + obase + 4 * lg + r;
            out[row * kL + nA] = acc0[r] + bias[r] + x[row * kL + nA];
            out[row * kL + nB] = acc1[r] + bias[r] + x[row * kL + nB];
        }
    }
}

// ---------------------------------------------------------------------------
extern "C" void kernel_launch(void* const* d_in, const int* in_sizes, int n_in,
                              void* d_out, int out_size, void* d_ws, size_t ws_size,
                              hipStream_t stream) {
    const float* x     = (const float*)d_in[0];
    const float* gn_w  = (const float*)d_in[1];
    const float* gn_b  = (const float*)d_in[2];
    const float* qkv_w = (const float*)d_in[3];
    const float* qkv_b = (const float*)d_in[4];
    const float* out_w = (const float*)d_in[5];
    const float* out_b = (const float*)d_in[6];
    float* out = (float*)d_out;

    char* ws = (char*)d_ws;
    const size_t MB = 1024 * 1024;
    unsigned short* hT   = (unsigned short*)(ws);             // 4 MB
    unsigned short* qT   = (unsigned short*)(ws + 4  * MB);   // 4 MB
    unsigned short* kT   = (unsigned short*)(ws + 8  * MB);   // 4 MB
    unsigned short* vbuf = (unsigned short*)(ws + 12 * MB);   // 4 MB
    unsigned short* h2T  = (unsigned short*)(ws + 16 * MB);   // 4 MB
    unsigned short* wqkv = (unsigned short*)(ws + 20 * MB);   // 384 KB
    unsigned short* wout = (unsigned short*)(ws + 20 * MB + 512 * 1024);

    gncvt_kernel<<<dim3(384), 256, 0, stream>>>(x, gn_w, gn_b, hT, qkv_w, out_w, wqkv, wout);
    qkv_gemm<<<dim3(16, 12, kB), 256, 0, stream>>>(wqkv, hT, qkv_b, qT, kT, vbuf);
    attn_kernel<<<dim3(4096), 64, 0, stream>>>(qT, kT, vbuf, h2T);
    out_gemm<<<dim3(32, 4, kB), 256, 0, stream>>>(wout, h2T, out_b, x, out);
}

// Round 12
// 108.062 us; speedup vs baseline: 1.8226x; 1.8226x over previous
//
#include <hip/hip_runtime.h>
#include <math.h>

using f32x4  = __attribute__((ext_vector_type(4))) float;
using bf16x8 = __attribute__((ext_vector_type(8))) short;

constexpr int kB = 4, kC = 256, kL = 2048, kH = 8;
constexpr float kQScale = 0.25505402264f;  // 1/sqrt(32) * log2(e)

__device__ __forceinline__ unsigned short f2bf(float f) {
    unsigned u = __builtin_bit_cast(unsigned, f);
    u += 0x7fffu + ((u >> 16) & 1u);
    return (unsigned short)(u >> 16);
}
__device__ __forceinline__ unsigned cvt_pk(float lo, float hi) {
    unsigned r;
    asm("v_cvt_pk_bf16_f32 %0, %1, %2" : "=v"(r) : "v"(lo), "v"(hi));
    return r;
}
__device__ __forceinline__ f32x4 mfma16(bf16x8 a, bf16x8 b, f32x4 c) {
    return __builtin_amdgcn_mfma_f32_16x16x32_bf16(a, b, c, 0, 0, 0);
}
__device__ __forceinline__ bf16x8 bc8(unsigned a, unsigned b, unsigned c, unsigned d) {
    return __builtin_bit_cast(bf16x8, make_uint4(a, b, c, d));
}

// ---------------------------------------------------------------------------
// Fused GN (blocks 0..127) + weight cvt (blocks 128..383): one launch stage.
// ---------------------------------------------------------------------------
__global__ __launch_bounds__(256) void gncvt_kernel(const float* __restrict__ x,
                                                    const float* __restrict__ gw,
                                                    const float* __restrict__ gb,
                                                    unsigned short* __restrict__ hT,
                                                    const float* __restrict__ qkvw,
                                                    const float* __restrict__ outw,
                                                    unsigned short* __restrict__ wq,
                                                    unsigned short* __restrict__ wo) {
    if (blockIdx.x >= 128) {  // ---- cvt role ----
        int i = (blockIdx.x - 128) * 256 + threadIdx.x;  // 0..65535 float4s
        const float* s; unsigned short* d; int j;
        if (i < 49152) { s = qkvw; d = wq; j = i; }
        else           { s = outw; d = wo; j = i - 49152; }
        float4 v = ((const float4*)s)[j];
        ((uint2*)d)[j] = make_uint2(cvt_pk(v.x, v.y), cvt_pk(v.z, v.w));
        return;
    }
    // ---- groupnorm role ----
    int b = blockIdx.x >> 5, g = blockIdx.x & 31;
    int t = threadIdx.x;
    const float* xp = x + ((size_t)b * kC + g * 8) * kL + 8 * t;

    float v[8][8];
    float s = 0.f, ss = 0.f;
#pragma unroll
    for (int c = 0; c < 8; ++c) {
        float4 a  = *(const float4*)(xp + (size_t)c * kL);
        float4 a2 = *(const float4*)(xp + (size_t)c * kL + 4);
        v[c][0]=a.x; v[c][1]=a.y; v[c][2]=a.z; v[c][3]=a.w;
        v[c][4]=a2.x; v[c][5]=a2.y; v[c][6]=a2.z; v[c][7]=a2.w;
        s  += (a.x+a.y)+(a.z+a.w)+(a2.x+a2.y)+(a2.z+a2.w);
        ss += a.x*a.x+a.y*a.y+a.z*a.z+a.w*a.w+a2.x*a2.x+a2.y*a2.y+a2.z*a2.z+a2.w*a2.w;
    }
#pragma unroll
    for (int off = 32; off; off >>= 1) {
        s  += __shfl_down(s, off);
        ss += __shfl_down(ss, off);
    }
    __shared__ float red[8];
    int wv = t >> 6;
    if ((t & 63) == 0) { red[wv] = s; red[4 + wv] = ss; }
    __syncthreads();
    s  = red[0] + red[1] + red[2] + red[3];
    ss = red[4] + red[5] + red[6] + red[7];
    float mean = s * (1.f / 16384.f);
    float var  = ss * (1.f / 16384.f) - mean * mean;
    float rstd = rsqrtf(var + 1e-5f);

    float wc[8], bc[8];
#pragma unroll
    for (int c = 0; c < 8; ++c) { wc[c] = gw[g*8+c] * rstd; bc[c] = gb[g*8+c]; }

    unsigned short* hp = hT + ((size_t)b * kL + 8 * t) * kC + g * 8;
#pragma unroll
    for (int j = 0; j < 8; ++j) {
        unsigned pk[4];
#pragma unroll
        for (int c2 = 0; c2 < 4; ++c2) {
            pk[c2] = cvt_pk((v[2*c2  ][j] - mean) * wc[2*c2  ] + bc[2*c2  ],
                            (v[2*c2+1][j] - mean) * wc[2*c2+1] + bc[2*c2+1]);
        }
        *(uint4*)(hp + (size_t)j * kC) = make_uint4(pk[0], pk[1], pk[2], pk[3]);
    }
}

// ---------------------------------------------------------------------------
// Merged QKV GEMM, W-in-registers. Block: o-tile 64 (wave=16 rows), n-tile 128.
// q,k stored transposed [B][H][L][32]; v stored [B][256][L].
// q pre-scaled by 1/sqrt(D)*log2(e), bias fused.
// ---------------------------------------------------------------------------
__device__ __forceinline__ void store_qk(unsigned short* __restrict__ base, size_t bh,
                                         int n, int d0, f32x4 acc,
                                         const float* bias4, float scale) {
    float v0 = (acc[0] + bias4[0]) * scale, v1 = (acc[1] + bias4[1]) * scale;
    float v2 = (acc[2] + bias4[2]) * scale, v3 = (acc[3] + bias4[3]) * scale;
    *(uint2*)(base + (bh * kL + n) * 32 + d0) = make_uint2(cvt_pk(v0, v1), cvt_pk(v2, v3));
}

__global__ __launch_bounds__(256) void qkv_gemm(const unsigned short* __restrict__ Wb,
                                                const unsigned short* __restrict__ hT,
                                                const float* __restrict__ qkvb,
                                                unsigned short* __restrict__ qT,
                                                unsigned short* __restrict__ kT,
                                                unsigned short* __restrict__ vbuf) {
    int t = threadIdx.x, wv = t >> 6, ll = t & 15, lg = (t >> 4) & 3;
    int n0 = blockIdx.x * 128, o0 = blockIdx.y * 64, b = blockIdx.z;
    int obase = o0 + wv * 16;
    const unsigned short* hb = hT + (size_t)b * kL * kC;

    bf16x8 wf[8];
#pragma unroll
    for (int k = 0; k < 8; ++k)
        wf[k] = *(const bf16x8*)(Wb + (size_t)(obase + ll) * 256 + 32 * k + 8 * lg);
    float bias[4];
#pragma unroll
    for (int r = 0; r < 4; ++r) bias[r] = qkvb[obase + 4 * lg + r];
    int mode = (obase < 256) ? 0 : (obase < 512 ? 1 : 2);
    int d0 = (obase & 31) + 4 * lg;

    for (int np = 0; np < 4; ++np) {
        f32x4 acc0 = {}, acc1 = {};
        int nA = n0 + np * 32 + ll, nB = nA + 16;
#pragma unroll
        for (int k = 0; k < 8; ++k) {
            bf16x8 h0 = *(const bf16x8*)(hb + (size_t)nA * 256 + 32 * k + 8 * lg);
            bf16x8 h1 = *(const bf16x8*)(hb + (size_t)nB * 256 + 32 * k + 8 * lg);
            acc0 = mfma16(wf[k], h0, acc0);
            acc1 = mfma16(wf[k], h1, acc1);
        }
        if (mode == 0) {
            size_t bh = (size_t)b * kH + (obase >> 5);
            store_qk(qT, bh, nA, d0, acc0, bias, kQScale);
            store_qk(qT, bh, nB, d0, acc1, bias, kQScale);
        } else if (mode == 1) {
            size_t bh = (size_t)b * kH + ((obase - 256) >> 5);
            store_qk(kT, bh, nA, d0, acc0, bias, 1.f);
            store_qk(kT, bh, nB, d0, acc1, bias, 1.f);
        } else {
#pragma unroll
            for (int r = 0; r < 4; ++r) {
                size_t row = (size_t)b * kC + (obase - 512) + 4 * lg + r;
                vbuf[row * kL + nA] = f2bf(acc0[r] + bias[r]);
                vbuf[row * kL + nB] = f2bf(acc1[r] + bias[r]);
            }
        }
    }
}

// ---------------------------------------------------------------------------
// Flash attention v12: split-K across waves, r10 wave body VERBATIM.
// Each wave: 32 queries x 1024 keys (half). kh selects the half. 4096 waves
// (= 4 waves/SIMD, 2x r10's TLP). Partials (fp32 acc + per-query lsum) go to
// workspace; attn_combine adds the two halves and normalizes (no-max softmax
// => plain addition is exact). Loop body, tile order, LDS stride-34 transpose
// and prefetch idiom identical to r10 (VGPR 84 build).
// ---------------------------------------------------------------------------
__global__ __launch_bounds__(64) void attn_kernel(const unsigned short* __restrict__ qT,
                                                  const unsigned short* __restrict__ kT,
                                                  const unsigned short* __restrict__ vbuf,
                                                  float* __restrict__ pacc,
                                                  float* __restrict__ plsum) {
    __shared__ unsigned Plds[32][34];
    int t = threadIdx.x, ll = t & 15, hi = (t >> 4) & 3;
    int j = blockIdx.x;
    int bid = (j & 7) * 512 + (j >> 3);   // XCD swizzle: 4096 = 8 x 512, bijective
    int kh = bid & 1;                     // key half
    int qt = (bid >> 1) & 63;             // qt 0..63 (32-q tiles)
    int bh = bid >> 7;                    // bh 0..31 (4 per XCD, same as r10)
    const unsigned short* qb = qT + (size_t)bh * kL * 32;
    const unsigned short* kb = kT + (size_t)bh * kL * 32;
    const unsigned short* vb = vbuf + (((size_t)(bh >> 3)) * kC + (bh & 7) * 32) * kL;
    int nbase = qt * 32;                  // this wave's 32 queries
    int kstart = kh * 1024;               // this wave's key half

    bf16x8 qf[2];
#pragma unroll
    for (int nj = 0; nj < 2; ++nj)
        qf[nj] = *(const bf16x8*)(qb + (size_t)(nbase + 16 * nj + ll) * 32 + 8 * hi);

    f32x4 acc[2][2] = {};                 // [nj][dj]
    float lsum[2] = {0.f, 0.f};
    const f32x4 zero = {0.f, 0.f, 0.f, 0.f};

    // prefetch tile 0 (r10 idiom: in-loop decls + end-of-loop copies)
    bf16x8 ka[4], va[2][2];
#pragma unroll
    for (int mj = 0; mj < 4; ++mj)
        ka[mj] = *(const bf16x8*)(kb + (size_t)(kstart + 16 * mj + ll) * 32 + 8 * hi);
#pragma unroll
    for (int dj = 0; dj < 2; ++dj)
#pragma unroll
        for (int tt = 0; tt < 2; ++tt)
            va[dj][tt] = *(const bf16x8*)(vb + (size_t)(16 * dj + ll) * kL + kstart + 32 * tt + 8 * hi);

#pragma unroll 2
    for (int it = 0; it < 16; ++it) {
        int m0 = kstart + it * 64;
        int mn = kstart + ((it * 64 + 64) & 1023);  // next tile (wraps, unused)
        bf16x8 nka[4], nva[2][2];
#pragma unroll
        for (int mj = 0; mj < 4; ++mj)
            nka[mj] = *(const bf16x8*)(kb + (size_t)(mn + 16 * mj + ll) * 32 + 8 * hi);
#pragma unroll
        for (int dj = 0; dj < 2; ++dj)
#pragma unroll
            for (int tt = 0; tt < 2; ++tt)
                nva[dj][tt] = *(const bf16x8*)(vb + (size_t)(16 * dj + ll) * kL + mn + 32 * tt + 8 * hi);

        // QK^T (swapped): s[mj][nj] = S^T[key m0+16mj+4hi+r][query nbase+16nj+ll]
        f32x4 s[4][2];
        __builtin_amdgcn_s_setprio(1);
#pragma unroll
        for (int mj = 0; mj < 4; ++mj)
#pragma unroll
            for (int nj = 0; nj < 2; ++nj)
                s[mj][nj] = mfma16(ka[mj], qf[nj], zero);
        __builtin_amdgcn_s_setprio(0);

        // p = exp2(s); lane-local lsum; pack to LDS (stride 34: conflict-free)
#pragma unroll
        for (int mj = 0; mj < 4; ++mj)
#pragma unroll
            for (int nj = 0; nj < 2; ++nj) {
                float p0 = __builtin_amdgcn_exp2f(s[mj][nj][0]);
                float p1 = __builtin_amdgcn_exp2f(s[mj][nj][1]);
                float p2 = __builtin_amdgcn_exp2f(s[mj][nj][2]);
                float p3 = __builtin_amdgcn_exp2f(s[mj][nj][3]);
                lsum[nj] += (p0 + p1) + (p2 + p3);
                *(uint2*)&Plds[16 * nj + ll][8 * mj + 2 * hi] =
                    make_uint2(cvt_pk(p0, p1), cvt_pk(p2, p3));
            }

        // read P as B-fragments: pbf[nj][tt] = P[keys m0+32tt+8hi..+7][query 16nj+ll]
        bf16x8 pbf[2][2];
#pragma unroll
        for (int nj = 0; nj < 2; ++nj)
#pragma unroll
            for (int tt = 0; tt < 2; ++tt) {
                uint2 lo  = *(uint2*)&Plds[16 * nj + ll][16 * tt + 4 * hi];
                uint2 hi2 = *(uint2*)&Plds[16 * nj + ll][16 * tt + 4 * hi + 2];
                pbf[nj][tt] = bc8(lo.x, lo.y, hi2.x, hi2.y);
            }

        __builtin_amdgcn_s_setprio(1);
#pragma unroll
        for (int tt = 0; tt < 2; ++tt)
#pragma unroll
            for (int nj = 0; nj < 2; ++nj)
#pragma unroll
                for (int dj = 0; dj < 2; ++dj)
                    acc[nj][dj] = mfma16(va[dj][tt], pbf[nj][tt], acc[nj][dj]);
        __builtin_amdgcn_s_setprio(0);

#pragma unroll
        for (int mj = 0; mj < 4; ++mj) ka[mj] = nka[mj];
#pragma unroll
        for (int dj = 0; dj < 2; ++dj)
#pragma unroll
            for (int tt = 0; tt < 2; ++tt) va[dj][tt] = nva[dj][tt];
    }

    // partial epilogue: fp32 acc + per-query lsum to workspace
    int w = (bh * 64 + qt) * 2 + kh;
    float* pa = pacc + (size_t)w * 1024;  // [32 q][32 d]
#pragma unroll
    for (int nj = 0; nj < 2; ++nj) {
#pragma unroll
        for (int dj = 0; dj < 2; ++dj)
            *(f32x4*)(pa + (16 * nj + ll) * 32 + 16 * dj + 4 * hi) = acc[nj][dj];
        lsum[nj] += __shfl_xor(lsum[nj], 16);
        lsum[nj] += __shfl_xor(lsum[nj], 32);
        if (hi == 0) plsum[w * 32 + 16 * nj + ll] = lsum[nj];
    }
}

// ---------------------------------------------------------------------------
// Combine split-K halves: out = (accA+accB)/(lA+lB), write h2T bf16 [B][L][C].
// One thread per query (65536 threads).
// ---------------------------------------------------------------------------
__global__ __launch_bounds__(256) void attn_combine(const float* __restrict__ pacc,
                                                    const float* __restrict__ plsum,
                                                    unsigned short* __restrict__ h2T) {
    int idx = blockIdx.x * 256 + threadIdx.x;   // 0..65535
    int bh = idx >> 11, rem = idx & 2047;       // rem = n
    int b = bh >> 3, h = bh & 7;
    int qt = rem >> 5, q = rem & 31;
    int w0 = (bh * 64 + qt) * 2;
    const float* a0 = pacc + (size_t)w0 * 1024 + q * 32;
    const float* a1 = a0 + 1024;
    float inv = 1.f / (plsum[w0 * 32 + q] + plsum[w0 * 32 + 32 + q]);
    unsigned short* ob = h2T + ((size_t)b * kL + rem) * kC + h * 32;
#pragma unroll
    for (int dd = 0; dd < 4; ++dd) {
        float4 x0 = *(const float4*)(a0 + dd * 8);
        float4 x1 = *(const float4*)(a1 + dd * 8);
        float4 y0 = *(const float4*)(a0 + dd * 8 + 4);
        float4 y1 = *(const float4*)(a1 + dd * 8 + 4);
        *(uint4*)(ob + dd * 8) = make_uint4(
            cvt_pk((x0.x + x1.x) * inv, (x0.y + x1.y) * inv),
            cvt_pk((x0.z + x1.z) * inv, (x0.w + x1.w) * inv),
            cvt_pk((y0.x + y1.x) * inv, (y0.y + y1.y) * inv),
            cvt_pk((y0.z + y1.z) * inv, (y0.w + y1.w) * inv));
    }
}

// ---------------------------------------------------------------------------
// OUT GEMM, W-in-registers. Block: o-tile 64 (wave=16), n-tile 64.
// out[o][n] = sum_c Wout[o][c] h2T[n][c] + bias + x, fp32 out.
// ---------------------------------------------------------------------------
__global__ __launch_bounds__(256) void out_gemm(const unsigned short* __restrict__ Wb,
                                                const unsigned short* __restrict__ h2T,
                                                const float* __restrict__ outb,
                                                const float* __restrict__ x,
                                                float* __restrict__ out) {
    int t = threadIdx.x, wv = t >> 6, ll = t & 15, lg = (t >> 4) & 3;
    int n0 = blockIdx.x * 64, o0 = blockIdx.y * 64, b = blockIdx.z;
    int obase = o0 + wv * 16;
    const unsigned short* hb = h2T + (size_t)b * kL * kC;

    bf16x8 wf[8];
#pragma unroll
    for (int k = 0; k < 8; ++k)
        wf[k] = *(const bf16x8*)(Wb + (size_t)(obase + ll) * 256 + 32 * k + 8 * lg);
    float bias[4];
#pragma unroll
    for (int r = 0; r < 4; ++r) bias[r] = outb[obase + 4 * lg + r];

    for (int np = 0; np < 2; ++np) {
        f32x4 acc0 = {}, acc1 = {};
        int nA = n0 + np * 32 + ll, nB = nA + 16;
#pragma unroll
        for (int k = 0; k < 8; ++k) {
            bf16x8 h0 = *(const bf16x8*)(hb + (size_t)nA * 256 + 32 * k + 8 * lg);
            bf16x8 h1 = *(const bf16x8*)(hb + (size_t)nB * 256 + 32 * k + 8 * lg);
            acc0 = mfma16(wf[k], h0, acc0);
            acc1 = mfma16(wf[k], h1, acc1);
        }
#pragma unroll
        for (int r = 0; r < 4; ++r) {
            size_t row = (size_t)b * kC + obase + 4 * lg + r;
            out[row * kL + nA] = acc0[r] + bias[r] + x[row * kL + nA];
            out[row * kL + nB] = acc1[r] + bias[r] + x[row * kL + nB];
        }
    }
}

// ---------------------------------------------------------------------------
extern "C" void kernel_launch(void* const* d_in, const int* in_sizes, int n_in,
                              void* d_out, int out_size, void* d_ws, size_t ws_size,
                              hipStream_t stream) {
    const float* x     = (const float*)d_in[0];
    const float* gn_w  = (const float*)d_in[1];
    const float* gn_b  = (const float*)d_in[2];
    const float* qkv_w = (const float*)d_in[3];
    const float* qkv_b = (const float*)d_in[4];
    const float* out_w = (const float*)d_in[5];
    const float* out_b = (const float*)d_in[6];
    float* out = (float*)d_out;

    char* ws = (char*)d_ws;
    const size_t MB = 1024 * 1024;
    unsigned short* hT   = (unsigned short*)(ws);             // 0-4 MB
    unsigned short* qT   = (unsigned short*)(ws + 4  * MB);   // 4-8 MB
    unsigned short* kT   = (unsigned short*)(ws + 8  * MB);   // 8-12 MB
    unsigned short* vbuf = (unsigned short*)(ws + 12 * MB);   // 12-16 MB
    unsigned short* h2T  = (unsigned short*)(ws + 16 * MB);   // 16-20 MB
    unsigned short* wqkv = (unsigned short*)(ws + 20 * MB);   // 20-20.375 MB
    unsigned short* wout = (unsigned short*)(ws + 20 * MB + 512 * 1024);
    float* pacc  = (float*)(ws + 21 * MB);                    // 21-37 MB
    float* plsum = (float*)(ws + 37 * MB);                    // 37-37.5 MB

    gncvt_kernel<<<dim3(384), 256, 0, stream>>>(x, gn_w, gn_b, hT, qkv_w, out_w, wqkv, wout);
    qkv_gemm<<<dim3(16, 12, kB), 256, 0, stream>>>(wqkv, hT, qkv_b, qT, kT, vbuf);
    attn_kernel<<<dim3(4096), 64, 0, stream>>>(qT, kT, vbuf, pacc, plsum);
    attn_combine<<<dim3(256), 256, 0, stream>>>(pacc, plsum, h2T);
    out_gemm<<<dim3(32, 4, kB), 256, 0, stream>>>(wout, h2T, out_b, x, out);
}

// Round 13
// 101.506 us; speedup vs baseline: 1.9403x; 1.0646x over previous
//
#include <hip/hip_runtime.h>
#include <math.h>

using f32x4  = __attribute__((ext_vector_type(4))) float;
using bf16x8 = __attribute__((ext_vector_type(8))) short;

constexpr int kB = 4, kC = 256, kL = 2048, kH = 8;
constexpr float kQScale = 0.25505402264f;  // 1/sqrt(32) * log2(e)

__device__ __forceinline__ unsigned short f2bf(float f) {
    unsigned u = __builtin_bit_cast(unsigned, f);
    u += 0x7fffu + ((u >> 16) & 1u);
    return (unsigned short)(u >> 16);
}
__device__ __forceinline__ unsigned cvt_pk(float lo, float hi) {
    unsigned r;
    asm("v_cvt_pk_bf16_f32 %0, %1, %2" : "=v"(r) : "v"(lo), "v"(hi));
    return r;
}
__device__ __forceinline__ f32x4 mfma16(bf16x8 a, bf16x8 b, f32x4 c) {
    return __builtin_amdgcn_mfma_f32_16x16x32_bf16(a, b, c, 0, 0, 0);
}
__device__ __forceinline__ bf16x8 bc8(unsigned a, unsigned b, unsigned c, unsigned d) {
    return __builtin_bit_cast(bf16x8, make_uint4(a, b, c, d));
}

// ---------------------------------------------------------------------------
// Fused GN (blocks 0..127) + weight cvt (blocks 128..383): one launch stage.
// ---------------------------------------------------------------------------
__global__ __launch_bounds__(256) void gncvt_kernel(const float* __restrict__ x,
                                                    const float* __restrict__ gw,
                                                    const float* __restrict__ gb,
                                                    unsigned short* __restrict__ hT,
                                                    const float* __restrict__ qkvw,
                                                    const float* __restrict__ outw,
                                                    unsigned short* __restrict__ wq,
                                                    unsigned short* __restrict__ wo) {
    if (blockIdx.x >= 128) {  // ---- cvt role ----
        int i = (blockIdx.x - 128) * 256 + threadIdx.x;  // 0..65535 float4s
        const float* s; unsigned short* d; int j;
        if (i < 49152) { s = qkvw; d = wq; j = i; }
        else           { s = outw; d = wo; j = i - 49152; }
        float4 v = ((const float4*)s)[j];
        ((uint2*)d)[j] = make_uint2(cvt_pk(v.x, v.y), cvt_pk(v.z, v.w));
        return;
    }
    // ---- groupnorm role ----
    int b = blockIdx.x >> 5, g = blockIdx.x & 31;
    int t = threadIdx.x;
    const float* xp = x + ((size_t)b * kC + g * 8) * kL + 8 * t;

    float v[8][8];
    float s = 0.f, ss = 0.f;
#pragma unroll
    for (int c = 0; c < 8; ++c) {
        float4 a  = *(const float4*)(xp + (size_t)c * kL);
        float4 a2 = *(const float4*)(xp + (size_t)c * kL + 4);
        v[c][0]=a.x; v[c][1]=a.y; v[c][2]=a.z; v[c][3]=a.w;
        v[c][4]=a2.x; v[c][5]=a2.y; v[c][6]=a2.z; v[c][7]=a2.w;
        s  += (a.x+a.y)+(a.z+a.w)+(a2.x+a2.y)+(a2.z+a2.w);
        ss += a.x*a.x+a.y*a.y+a.z*a.z+a.w*a.w+a2.x*a2.x+a2.y*a2.y+a2.z*a2.z+a2.w*a2.w;
    }
#pragma unroll
    for (int off = 32; off; off >>= 1) {
        s  += __shfl_down(s, off);
        ss += __shfl_down(ss, off);
    }
    __shared__ float red[8];
    int wv = t >> 6;
    if ((t & 63) == 0) { red[wv] = s; red[4 + wv] = ss; }
    __syncthreads();
    s  = red[0] + red[1] + red[2] + red[3];
    ss = red[4] + red[5] + red[6] + red[7];
    float mean = s * (1.f / 16384.f);
    float var  = ss * (1.f / 16384.f) - mean * mean;
    float rstd = rsqrtf(var + 1e-5f);

    float wc[8], bc[8];
#pragma unroll
    for (int c = 0; c < 8; ++c) { wc[c] = gw[g*8+c] * rstd; bc[c] = gb[g*8+c]; }

    unsigned short* hp = hT + ((size_t)b * kL + 8 * t) * kC + g * 8;
#pragma unroll
    for (int j = 0; j < 8; ++j) {
        unsigned pk[4];
#pragma unroll
        for (int c2 = 0; c2 < 4; ++c2) {
            pk[c2] = cvt_pk((v[2*c2  ][j] - mean) * wc[2*c2  ] + bc[2*c2  ],
                            (v[2*c2+1][j] - mean) * wc[2*c2+1] + bc[2*c2+1]);
        }
        *(uint4*)(hp + (size_t)j * kC) = make_uint4(pk[0], pk[1], pk[2], pk[3]);
    }
}

// ---------------------------------------------------------------------------
// Merged QKV GEMM, W-in-registers. Block: o-tile 64 (wave=16 rows), n-tile 128.
// q,k stored transposed [B][H][L][32]; v stored [B][256][L].
// q pre-scaled by 1/sqrt(D)*log2(e), bias fused.
// ---------------------------------------------------------------------------
__device__ __forceinline__ void store_qk(unsigned short* __restrict__ base, size_t bh,
                                         int n, int d0, f32x4 acc,
                                         const float* bias4, float scale) {
    float v0 = (acc[0] + bias4[0]) * scale, v1 = (acc[1] + bias4[1]) * scale;
    float v2 = (acc[2] + bias4[2]) * scale, v3 = (acc[3] + bias4[3]) * scale;
    *(uint2*)(base + (bh * kL + n) * 32 + d0) = make_uint2(cvt_pk(v0, v1), cvt_pk(v2, v3));
}

__global__ __launch_bounds__(256) void qkv_gemm(const unsigned short* __restrict__ Wb,
                                                const unsigned short* __restrict__ hT,
                                                const float* __restrict__ qkvb,
                                                unsigned short* __restrict__ qT,
                                                unsigned short* __restrict__ kT,
                                                unsigned short* __restrict__ vbuf) {
    int t = threadIdx.x, wv = t >> 6, ll = t & 15, lg = (t >> 4) & 3;
    int n0 = blockIdx.x * 128, o0 = blockIdx.y * 64, b = blockIdx.z;
    int obase = o0 + wv * 16;
    const unsigned short* hb = hT + (size_t)b * kL * kC;

    bf16x8 wf[8];
#pragma unroll
    for (int k = 0; k < 8; ++k)
        wf[k] = *(const bf16x8*)(Wb + (size_t)(obase + ll) * 256 + 32 * k + 8 * lg);
    float bias[4];
#pragma unroll
    for (int r = 0; r < 4; ++r) bias[r] = qkvb[obase + 4 * lg + r];
    int mode = (obase < 256) ? 0 : (obase < 512 ? 1 : 2);
    int d0 = (obase & 31) + 4 * lg;

    for (int np = 0; np < 4; ++np) {
        f32x4 acc0 = {}, acc1 = {};
        int nA = n0 + np * 32 + ll, nB = nA + 16;
#pragma unroll
        for (int k = 0; k < 8; ++k) {
            bf16x8 h0 = *(const bf16x8*)(hb + (size_t)nA * 256 + 32 * k + 8 * lg);
            bf16x8 h1 = *(const bf16x8*)(hb + (size_t)nB * 256 + 32 * k + 8 * lg);
            acc0 = mfma16(wf[k], h0, acc0);
            acc1 = mfma16(wf[k], h1, acc1);
        }
        if (mode == 0) {
            size_t bh = (size_t)b * kH + (obase >> 5);
            store_qk(qT, bh, nA, d0, acc0, bias, kQScale);
            store_qk(qT, bh, nB, d0, acc1, bias, kQScale);
        } else if (mode == 1) {
            size_t bh = (size_t)b * kH + ((obase - 256) >> 5);
            store_qk(kT, bh, nA, d0, acc0, bias, 1.f);
            store_qk(kT, bh, nB, d0, acc1, bias, 1.f);
        } else {
#pragma unroll
            for (int r = 0; r < 4; ++r) {
                size_t row = (size_t)b * kC + (obase - 512) + 4 * lg + r;
                vbuf[row * kL + nA] = f2bf(acc0[r] + bias[r]);
                vbuf[row * kL + nB] = f2bf(acc1[r] + bias[r]);
            }
        }
    }
}

// ---------------------------------------------------------------------------
// Flash attention v13: r12 split-K wave body VERBATIM, repackaged as 4-wave
// blocks to beat the ~6-workgroup/CU residency cap (r10/r12: 1-wave blocks
// pinned at ~17% occupancy regardless of grid; r3's 4-wave blocks hit 42%).
// Block = 4 waves: wave (wv&1) picks the qt of the block's qt-pair, (wv>>1)
// picks the key half. In-block split-K combine through padded LDS (r6's
// validated mechanism): kh=1 waves dump fp32 acc+lsum, barrier, kh=0 waves
// add + normalize + store h2T. No partial workspace, no combine kernel.
// Grid 1024 (= 8 XCD x 128), 256 threads.
// ---------------------------------------------------------------------------
__global__ __launch_bounds__(256) void attn_kernel(const unsigned short* __restrict__ qT,
                                                   const unsigned short* __restrict__ kT,
                                                   const unsigned short* __restrict__ vbuf,
                                                   unsigned short* __restrict__ h2T) {
    __shared__ unsigned Plds[4][32][34];
    __shared__ float comb[2][32][33];
    __shared__ float combl[2][32];
    int t = threadIdx.x, wv = t >> 6, ll = t & 15, hi = (t >> 4) & 3;
    int j = blockIdx.x;
    int bid = (j & 7) * 128 + (j >> 3);   // XCD swizzle: 1024 = 8 x 128, bijective
    int qp = bid & 31, bh = bid >> 5;     // qt-pair 0..31, bh 0..31 (4 heads/XCD)
    int qt = qp * 2 + (wv & 1);           // this wave's 32-query tile
    int kh = wv >> 1;                     // this wave's key half
    const unsigned short* qb = qT + (size_t)bh * kL * 32;
    const unsigned short* kb = kT + (size_t)bh * kL * 32;
    const unsigned short* vb = vbuf + (((size_t)(bh >> 3)) * kC + (bh & 7) * 32) * kL;
    int nbase = qt * 32;                  // this wave's 32 queries
    int kstart = kh * 1024;               // this wave's key half

    bf16x8 qf[2];
#pragma unroll
    for (int nj = 0; nj < 2; ++nj)
        qf[nj] = *(const bf16x8*)(qb + (size_t)(nbase + 16 * nj + ll) * 32 + 8 * hi);

    f32x4 acc[2][2] = {};                 // [nj][dj]
    float lsum[2] = {0.f, 0.f};
    const f32x4 zero = {0.f, 0.f, 0.f, 0.f};

    // prefetch tile 0 (r10/r12 idiom: in-loop decls + end-of-loop copies)
    bf16x8 ka[4], va[2][2];
#pragma unroll
    for (int mj = 0; mj < 4; ++mj)
        ka[mj] = *(const bf16x8*)(kb + (size_t)(kstart + 16 * mj + ll) * 32 + 8 * hi);
#pragma unroll
    for (int dj = 0; dj < 2; ++dj)
#pragma unroll
        for (int tt = 0; tt < 2; ++tt)
            va[dj][tt] = *(const bf16x8*)(vb + (size_t)(16 * dj + ll) * kL + kstart + 32 * tt + 8 * hi);

#pragma unroll 2
    for (int it = 0; it < 16; ++it) {
        int mn = kstart + ((it * 64 + 64) & 1023);  // next tile (wraps, unused)
        bf16x8 nka[4], nva[2][2];
#pragma unroll
        for (int mj = 0; mj < 4; ++mj)
            nka[mj] = *(const bf16x8*)(kb + (size_t)(mn + 16 * mj + ll) * 32 + 8 * hi);
#pragma unroll
        for (int dj = 0; dj < 2; ++dj)
#pragma unroll
            for (int tt = 0; tt < 2; ++tt)
                nva[dj][tt] = *(const bf16x8*)(vb + (size_t)(16 * dj + ll) * kL + mn + 32 * tt + 8 * hi);

        // QK^T (swapped): s[mj][nj] = S^T[key 16mj+4hi+r][query nbase+16nj+ll]
        f32x4 s[4][2];
        __builtin_amdgcn_s_setprio(1);
#pragma unroll
        for (int mj = 0; mj < 4; ++mj)
#pragma unroll
            for (int nj = 0; nj < 2; ++nj)
                s[mj][nj] = mfma16(ka[mj], qf[nj], zero);
        __builtin_amdgcn_s_setprio(0);

        // p = exp2(s); lane-local lsum; pack to LDS (stride 34: conflict-free)
#pragma unroll
        for (int mj = 0; mj < 4; ++mj)
#pragma unroll
            for (int nj = 0; nj < 2; ++nj) {
                float p0 = __builtin_amdgcn_exp2f(s[mj][nj][0]);
                float p1 = __builtin_amdgcn_exp2f(s[mj][nj][1]);
                float p2 = __builtin_amdgcn_exp2f(s[mj][nj][2]);
                float p3 = __builtin_amdgcn_exp2f(s[mj][nj][3]);
                lsum[nj] += (p0 + p1) + (p2 + p3);
                *(uint2*)&Plds[wv][16 * nj + ll][8 * mj + 2 * hi] =
                    make_uint2(cvt_pk(p0, p1), cvt_pk(p2, p3));
            }

        // read P as B-fragments
        bf16x8 pbf[2][2];
#pragma unroll
        for (int nj = 0; nj < 2; ++nj)
#pragma unroll
            for (int tt = 0; tt < 2; ++tt) {
                uint2 lo  = *(uint2*)&Plds[wv][16 * nj + ll][16 * tt + 4 * hi];
                uint2 hi2 = *(uint2*)&Plds[wv][16 * nj + ll][16 * tt + 4 * hi + 2];
                pbf[nj][tt] = bc8(lo.x, lo.y, hi2.x, hi2.y);
            }

        __builtin_amdgcn_s_setprio(1);
#pragma unroll
        for (int tt = 0; tt < 2; ++tt)
#pragma unroll
            for (int nj = 0; nj < 2; ++nj)
#pragma unroll
                for (int dj = 0; dj < 2; ++dj)
                    acc[nj][dj] = mfma16(va[dj][tt], pbf[nj][tt], acc[nj][dj]);
        __builtin_amdgcn_s_setprio(0);

#pragma unroll
        for (int mj = 0; mj < 4; ++mj) ka[mj] = nka[mj];
#pragma unroll
        for (int dj = 0; dj < 2; ++dj)
#pragma unroll
            for (int tt = 0; tt < 2; ++tt) va[dj][tt] = nva[dj][tt];
    }

    // per-wave lsum reduce (full row sums in every lane)
#pragma unroll
    for (int nj = 0; nj < 2; ++nj) {
        lsum[nj] += __shfl_xor(lsum[nj], 16);
        lsum[nj] += __shfl_xor(lsum[nj], 32);
    }

    // in-block split-K combine (r6 mechanism): kh=1 dumps, kh=0 finalizes
    if (kh == 1) {
        int sidx = wv & 1;
#pragma unroll
        for (int nj = 0; nj < 2; ++nj) {
#pragma unroll
            for (int dj = 0; dj < 2; ++dj)
                *(f32x4*)&comb[sidx][16 * nj + ll][16 * dj + 4 * hi] = acc[nj][dj];
            if (hi == 0) combl[sidx][16 * nj + ll] = lsum[nj];
        }
    }
    __syncthreads();
    if (kh == 0) {
        int sidx = wv & 1;
#pragma unroll
        for (int nj = 0; nj < 2; ++nj) {
            float ltot = lsum[nj] + combl[sidx][16 * nj + ll];
            float inv = 1.f / ltot;
            unsigned short* ob = h2T + (((size_t)(bh >> 3)) * kL + nbase + 16 * nj + ll) * kC + (bh & 7) * 32;
#pragma unroll
            for (int dj = 0; dj < 2; ++dj) {
                f32x4 other = *(f32x4*)&comb[sidx][16 * nj + ll][16 * dj + 4 * hi];
                float a0 = acc[nj][dj][0] + other[0];
                float a1 = acc[nj][dj][1] + other[1];
                float a2 = acc[nj][dj][2] + other[2];
                float a3 = acc[nj][dj][3] + other[3];
                *(uint2*)(ob + 16 * dj + 4 * hi) =
                    make_uint2(cvt_pk(a0 * inv, a1 * inv), cvt_pk(a2 * inv, a3 * inv));
            }
        }
    }
}

// ---------------------------------------------------------------------------
// OUT GEMM, W-in-registers. Block: o-tile 64 (wave=16), n-tile 64.
// out[o][n] = sum_c Wout[o][c] h2T[n][c] + bias + x, fp32 out.
// ---------------------------------------------------------------------------
__global__ __launch_bounds__(256) void out_gemm(const unsigned short* __restrict__ Wb,
                                                const unsigned short* __restrict__ h2T,
                                                const float* __restrict__ outb,
                                                const float* __restrict__ x,
                                                float* __restrict__ out) {
    int t = threadIdx.x, wv = t >> 6, ll = t & 15, lg = (t >> 4) & 3;
    int n0 = blockIdx.x * 64, o0 = blockIdx.y * 64, b = blockIdx.z;
    int obase = o0 + wv * 16;
    const unsigned short* hb = h2T + (size_t)b * kL * kC;

    bf16x8 wf[8];
#pragma unroll
    for (int k = 0; k < 8; ++k)
        wf[k] = *(const bf16x8*)(Wb + (size_t)(obase + ll) * 256 + 32 * k + 8 * lg);
    float bias[4];
#pragma unroll
    for (int r = 0; r < 4; ++r) bias[r] = outb[obase + 4 * lg + r];

    for (int np = 0; np < 2; ++np) {
        f32x4 acc0 = {}, acc1 = {};
        int nA = n0 + np * 32 + ll, nB = nA + 16;
#pragma unroll
        for (int k = 0; k < 8; ++k) {
            bf16x8 h0 = *(const bf16x8*)(hb + (size_t)nA * 256 + 32 * k + 8 * lg);
            bf16x8 h1 = *(const bf16x8*)(hb + (size_t)nB * 256 + 32 * k + 8 * lg);
            acc0 = mfma16(wf[k], h0, acc0);
            acc1 = mfma16(wf[k], h1, acc1);
        }
#pragma unroll
        for (int r = 0; r < 4; ++r) {
            size_t row = (size_t)b * kC + obase + 4 * lg + r;
            out[row * kL + nA] = acc0[r] + bias[r] + x[row * kL + nA];
            out[row * kL + nB] = acc1[r] + bias[r] + x[row * kL + nB];
        }
    }
}

// ---------------------------------------------------------------------------
extern "C" void kernel_launch(void* const* d_in, const int* in_sizes, int n_in,
                              void* d_out, int out_size, void* d_ws, size_t ws_size,
                              hipStream_t stream) {
    const float* x     = (const float*)d_in[0];
    const float* gn_w  = (const float*)d_in[1];
    const float* gn_b  = (const float*)d_in[2];
    const float* qkv_w = (const float*)d_in[3];
    const float* qkv_b = (const float*)d_in[4];
    const float* out_w = (const float*)d_in[5];
    const float* out_b = (const float*)d_in[6];
    float* out = (float*)d_out;

    char* ws = (char*)d_ws;
    const size_t MB = 1024 * 1024;
    unsigned short* hT   = (unsigned short*)(ws);             // 0-4 MB
    unsigned short* qT   = (unsigned short*)(ws + 4  * MB);   // 4-8 MB
    unsigned short* kT   = (unsigned short*)(ws + 8  * MB);   // 8-12 MB
    unsigned short* vbuf = (unsigned short*)(ws + 12 * MB);   // 12-16 MB
    unsigned short* h2T  = (unsigned short*)(ws + 16 * MB);   // 16-20 MB
    unsigned short* wqkv = (unsigned short*)(ws + 20 * MB);   // 20-20.375 MB
    unsigned short* wout = (unsigned short*)(ws + 20 * MB + 512 * 1024);

    gncvt_kernel<<<dim3(384), 256, 0, stream>>>(x, gn_w, gn_b, hT, qkv_w, out_w, wqkv, wout);
    qkv_gemm<<<dim3(16, 12, kB), 256, 0, stream>>>(wqkv, hT, qkv_b, qT, kT, vbuf);
    attn_kernel<<<dim3(1024), 256, 0, stream>>>(qT, kT, vbuf, h2T);
    out_gemm<<<dim3(32, 4, kB), 256, 0, stream>>>(wout, h2T, out_b, x, out);
}

// Round 14
// 92.462 us; speedup vs baseline: 2.1301x; 1.0978x over previous
//
#include <hip/hip_runtime.h>
#include <math.h>

using f32x4  = __attribute__((ext_vector_type(4))) float;
using bf16x8 = __attribute__((ext_vector_type(8))) short;

constexpr int kB = 4, kC = 256, kL = 2048, kH = 8;
constexpr float kQScale = 0.25505402264f;  // 1/sqrt(32) * log2(e)

__device__ __forceinline__ unsigned short f2bf(float f) {
    unsigned u = __builtin_bit_cast(unsigned, f);
    u += 0x7fffu + ((u >> 16) & 1u);
    return (unsigned short)(u >> 16);
}
__device__ __forceinline__ unsigned cvt_pk(float lo, float hi) {
    unsigned r;
    asm("v_cvt_pk_bf16_f32 %0, %1, %2" : "=v"(r) : "v"(lo), "v"(hi));
    return r;
}
__device__ __forceinline__ f32x4 mfma16(bf16x8 a, bf16x8 b, f32x4 c) {
    return __builtin_amdgcn_mfma_f32_16x16x32_bf16(a, b, c, 0, 0, 0);
}
__device__ __forceinline__ bf16x8 bc8(unsigned a, unsigned b, unsigned c, unsigned d) {
    return __builtin_bit_cast(bf16x8, make_uint4(a, b, c, d));
}
// async global->LDS, 16B per lane; LDS dest = base + lane*16 (HW-linear).
__device__ __forceinline__ void glds16(const unsigned short* g, unsigned short* l) {
    __builtin_amdgcn_global_load_lds(
        (const __attribute__((address_space(1))) unsigned int*)g,
        (__attribute__((address_space(3))) unsigned int*)l, 16, 0, 0);
}

// ---------------------------------------------------------------------------
// Fused GN (blocks 0..127) + weight cvt (blocks 128..383): one launch stage.
// ---------------------------------------------------------------------------
__global__ __launch_bounds__(256) void gncvt_kernel(const float* __restrict__ x,
                                                    const float* __restrict__ gw,
                                                    const float* __restrict__ gb,
                                                    unsigned short* __restrict__ hT,
                                                    const float* __restrict__ qkvw,
                                                    const float* __restrict__ outw,
                                                    unsigned short* __restrict__ wq,
                                                    unsigned short* __restrict__ wo) {
    if (blockIdx.x >= 128) {  // ---- cvt role ----
        int i = (blockIdx.x - 128) * 256 + threadIdx.x;  // 0..65535 float4s
        const float* s; unsigned short* d; int j;
        if (i < 49152) { s = qkvw; d = wq; j = i; }
        else           { s = outw; d = wo; j = i - 49152; }
        float4 v = ((const float4*)s)[j];
        ((uint2*)d)[j] = make_uint2(cvt_pk(v.x, v.y), cvt_pk(v.z, v.w));
        return;
    }
    // ---- groupnorm role ----
    int b = blockIdx.x >> 5, g = blockIdx.x & 31;
    int t = threadIdx.x;
    const float* xp = x + ((size_t)b * kC + g * 8) * kL + 8 * t;

    float v[8][8];
    float s = 0.f, ss = 0.f;
#pragma unroll
    for (int c = 0; c < 8; ++c) {
        float4 a  = *(const float4*)(xp + (size_t)c * kL);
        float4 a2 = *(const float4*)(xp + (size_t)c * kL + 4);
        v[c][0]=a.x; v[c][1]=a.y; v[c][2]=a.z; v[c][3]=a.w;
        v[c][4]=a2.x; v[c][5]=a2.y; v[c][6]=a2.z; v[c][7]=a2.w;
        s  += (a.x+a.y)+(a.z+a.w)+(a2.x+a2.y)+(a2.z+a2.w);
        ss += a.x*a.x+a.y*a.y+a.z*a.z+a.w*a.w+a2.x*a2.x+a2.y*a2.y+a2.z*a2.z+a2.w*a2.w;
    }
#pragma unroll
    for (int off = 32; off; off >>= 1) {
        s  += __shfl_down(s, off);
        ss += __shfl_down(ss, off);
    }
    __shared__ float red[8];
    int wv = t >> 6;
    if ((t & 63) == 0) { red[wv] = s; red[4 + wv] = ss; }
    __syncthreads();
    s  = red[0] + red[1] + red[2] + red[3];
    ss = red[4] + red[5] + red[6] + red[7];
    float mean = s * (1.f / 16384.f);
    float var  = ss * (1.f / 16384.f) - mean * mean;
    float rstd = rsqrtf(var + 1e-5f);

    float wc[8], bc[8];
#pragma unroll
    for (int c = 0; c < 8; ++c) { wc[c] = gw[g*8+c] * rstd; bc[c] = gb[g*8+c]; }

    unsigned short* hp = hT + ((size_t)b * kL + 8 * t) * kC + g * 8;
#pragma unroll
    for (int j = 0; j < 8; ++j) {
        unsigned pk[4];
#pragma unroll
        for (int c2 = 0; c2 < 4; ++c2) {
            pk[c2] = cvt_pk((v[2*c2  ][j] - mean) * wc[2*c2  ] + bc[2*c2  ],
                            (v[2*c2+1][j] - mean) * wc[2*c2+1] + bc[2*c2+1]);
        }
        *(uint4*)(hp + (size_t)j * kC) = make_uint4(pk[0], pk[1], pk[2], pk[3]);
    }
}

// ---------------------------------------------------------------------------
// Merged QKV GEMM, W-in-registers. Block: o-tile 64 (wave=16 rows), n-tile 128.
// q,k stored transposed [B][H][L][32]; v stored [B][256][L].
// q pre-scaled by 1/sqrt(D)*log2(e), bias fused.
// ---------------------------------------------------------------------------
__device__ __forceinline__ void store_qk(unsigned short* __restrict__ base, size_t bh,
                                         int n, int d0, f32x4 acc,
                                         const float* bias4, float scale) {
    float v0 = (acc[0] + bias4[0]) * scale, v1 = (acc[1] + bias4[1]) * scale;
    float v2 = (acc[2] + bias4[2]) * scale, v3 = (acc[3] + bias4[3]) * scale;
    *(uint2*)(base + (bh * kL + n) * 32 + d0) = make_uint2(cvt_pk(v0, v1), cvt_pk(v2, v3));
}

__global__ __launch_bounds__(256) void qkv_gemm(const unsigned short* __restrict__ Wb,
                                                const unsigned short* __restrict__ hT,
                                                const float* __restrict__ qkvb,
                                                unsigned short* __restrict__ qT,
                                                unsigned short* __restrict__ kT,
                                                unsigned short* __restrict__ vbuf) {
    int t = threadIdx.x, wv = t >> 6, ll = t & 15, lg = (t >> 4) & 3;
    int n0 = blockIdx.x * 128, o0 = blockIdx.y * 64, b = blockIdx.z;
    int obase = o0 + wv * 16;
    const unsigned short* hb = hT + (size_t)b * kL * kC;

    bf16x8 wf[8];
#pragma unroll
    for (int k = 0; k < 8; ++k)
        wf[k] = *(const bf16x8*)(Wb + (size_t)(obase + ll) * 256 + 32 * k + 8 * lg);
    float bias[4];
#pragma unroll
    for (int r = 0; r < 4; ++r) bias[r] = qkvb[obase + 4 * lg + r];
    int mode = (obase < 256) ? 0 : (obase < 512 ? 1 : 2);
    int d0 = (obase & 31) + 4 * lg;

    for (int np = 0; np < 4; ++np) {
        f32x4 acc0 = {}, acc1 = {};
        int nA = n0 + np * 32 + ll, nB = nA + 16;
#pragma unroll
        for (int k = 0; k < 8; ++k) {
            bf16x8 h0 = *(const bf16x8*)(hb + (size_t)nA * 256 + 32 * k + 8 * lg);
            bf16x8 h1 = *(const bf16x8*)(hb + (size_t)nB * 256 + 32 * k + 8 * lg);
            acc0 = mfma16(wf[k], h0, acc0);
            acc1 = mfma16(wf[k], h1, acc1);
        }
        if (mode == 0) {
            size_t bh = (size_t)b * kH + (obase >> 5);
            store_qk(qT, bh, nA, d0, acc0, bias, kQScale);
            store_qk(qT, bh, nB, d0, acc1, bias, kQScale);
        } else if (mode == 1) {
            size_t bh = (size_t)b * kH + ((obase - 256) >> 5);
            store_qk(kT, bh, nA, d0, acc0, bias, 1.f);
            store_qk(kT, bh, nB, d0, acc1, bias, 1.f);
        } else {
#pragma unroll
            for (int r = 0; r < 4; ++r) {
                size_t row = (size_t)b * kC + (obase - 512) + 4 * lg + r;
                vbuf[row * kL + nA] = f2bf(acc0[r] + bias[r]);
                vbuf[row * kL + nB] = f2bf(acc1[r] + bias[r]);
            }
        }
    }
}

// ---------------------------------------------------------------------------
// Flash attention v14: structural 2-phase LDS pipeline, K AND V both staged
// (fixes r8's exposed direct V-loads), tiles shared by all 4 waves of the
// block (4x load amortization vs r13). Wave math = r10 VERBATIM (full 2048
// keys/wave, same tile order, Plds stride-34 transpose, same lsum order ->
// bit-identical output).
// Block = 4 waves x 32q = 128 queries, one bh. Grid 512, XCD-swizzled.
// Per iter: each wave issues 2 glds16 (its K sub-tile + its V sub-tile) for
// tile t+1, then ds_reads tile t fragments (conflict-free b128), computes,
// one barrier. Stage latency hides under the ~450-cyc compute phase.
// No register prefetch -> VGPR drops ~88 -> ~70 (residency correlate).
// ---------------------------------------------------------------------------
__global__ __launch_bounds__(256) void attn_kernel(const unsigned short* __restrict__ qT,
                                                   const unsigned short* __restrict__ kT,
                                                   const unsigned short* __restrict__ vbuf,
                                                   unsigned short* __restrict__ h2T) {
    __shared__ alignas(16) unsigned short Klds[2][4][512];  // [buf][mj][frag order]
    __shared__ alignas(16) unsigned short Vlds[2][4][512];  // [buf][dj*2+tt][frag]
    __shared__ unsigned Plds[4][32][34];
    int t = threadIdx.x, wv = t >> 6, ll = t & 15, hi = (t >> 4) & 3;
    int lane = t & 63;
    int j = blockIdx.x;
    int bid = (j & 7) * 64 + (j >> 3);    // XCD swizzle: 512 = 8 x 64, bijective
    int qg = bid & 15, bh = bid >> 4;     // qg 0..15 (128-q groups), bh 0..31
    int b = bh >> 3, h = bh & 7;
    const unsigned short* qb = qT + (size_t)bh * kL * 32;
    const unsigned short* kb = kT + (size_t)bh * kL * 32;
    const unsigned short* vb = vbuf + ((size_t)b * kC + h * 32) * kL;
    int nbase = qg * 128 + wv * 32;       // this wave's 32 queries

    bf16x8 qf[2];
#pragma unroll
    for (int nj = 0; nj < 2; ++nj)
        qf[nj] = *(const bf16x8*)(qb + (size_t)(nbase + 16 * nj + ll) * 32 + 8 * hi);

    f32x4 acc[2][2] = {};                 // [nj][dj]
    float lsum[2] = {0.f, 0.f};
    const f32x4 zero = {0.f, 0.f, 0.f, 0.f};

    // per-lane global source offsets for this wave's staging assignments:
    // K sub-tile mj = wv: key = 16*wv + ll, d-range 8*hi
    const unsigned short* ksrc = kb + (size_t)(16 * wv + ll) * 32 + 8 * hi;
    // V sub-tile (dj,tt) = (wv>>1, wv&1): d = 16*(wv>>1)+ll, keys 32*(wv&1)+8*hi
    const unsigned short* vsrc = vb + (size_t)(16 * (wv >> 1) + ll) * kL + 32 * (wv & 1) + 8 * hi;

    // prologue: stage tile 0 into buf 0
    glds16(ksrc, &Klds[0][wv][0]);
    glds16(vsrc, &Vlds[0][wv][0]);
    __syncthreads();

    int cur = 0;
    for (int it = 0; it < 32; ++it) {
        int m0 = it * 64;
        if (it < 31) {  // stage next tile into the other buffer
            glds16(ksrc + (size_t)(m0 + 64) * 32, &Klds[cur ^ 1][wv][0]);
            glds16(vsrc + m0 + 64,                &Vlds[cur ^ 1][wv][0]);
        }

        // tile-t fragments from LDS (fragment-ordered, conflict-free b128)
        bf16x8 ka[4], va[2][2];
#pragma unroll
        for (int mj = 0; mj < 4; ++mj)
            ka[mj] = *(const bf16x8*)&Klds[cur][mj][lane * 8];
#pragma unroll
        for (int dj = 0; dj < 2; ++dj)
#pragma unroll
            for (int tt = 0; tt < 2; ++tt)
                va[dj][tt] = *(const bf16x8*)&Vlds[cur][dj * 2 + tt][lane * 8];

        // QK^T (swapped): s[mj][nj] = S^T[key m0+16mj+4hi+r][query nbase+16nj+ll]
        f32x4 s[4][2];
        __builtin_amdgcn_s_setprio(1);
#pragma unroll
        for (int mj = 0; mj < 4; ++mj)
#pragma unroll
            for (int nj = 0; nj < 2; ++nj)
                s[mj][nj] = mfma16(ka[mj], qf[nj], zero);
        __builtin_amdgcn_s_setprio(0);

        // p = exp2(s); lane-local lsum; pack to LDS (stride 34: conflict-free)
#pragma unroll
        for (int mj = 0; mj < 4; ++mj)
#pragma unroll
            for (int nj = 0; nj < 2; ++nj) {
                float p0 = __builtin_amdgcn_exp2f(s[mj][nj][0]);
                float p1 = __builtin_amdgcn_exp2f(s[mj][nj][1]);
                float p2 = __builtin_amdgcn_exp2f(s[mj][nj][2]);
                float p3 = __builtin_amdgcn_exp2f(s[mj][nj][3]);
                lsum[nj] += (p0 + p1) + (p2 + p3);
                *(uint2*)&Plds[wv][16 * nj + ll][8 * mj + 2 * hi] =
                    make_uint2(cvt_pk(p0, p1), cvt_pk(p2, p3));
            }

        // read P as B-fragments
        bf16x8 pbf[2][2];
#pragma unroll
        for (int nj = 0; nj < 2; ++nj)
#pragma unroll
            for (int tt = 0; tt < 2; ++tt) {
                uint2 lo  = *(uint2*)&Plds[wv][16 * nj + ll][16 * tt + 4 * hi];
                uint2 hi2 = *(uint2*)&Plds[wv][16 * nj + ll][16 * tt + 4 * hi + 2];
                pbf[nj][tt] = bc8(lo.x, lo.y, hi2.x, hi2.y);
            }

        __builtin_amdgcn_s_setprio(1);
#pragma unroll
        for (int tt = 0; tt < 2; ++tt)
#pragma unroll
            for (int nj = 0; nj < 2; ++nj)
#pragma unroll
                for (int dj = 0; dj < 2; ++dj)
                    acc[nj][dj] = mfma16(va[dj][tt], pbf[nj][tt], acc[nj][dj]);
        __builtin_amdgcn_s_setprio(0);

        __syncthreads();  // publishes buf^1 (stage drained) + protects buf reuse
        cur ^= 1;
    }

#pragma unroll
    for (int nj = 0; nj < 2; ++nj) {
        lsum[nj] += __shfl_xor(lsum[nj], 16);
        lsum[nj] += __shfl_xor(lsum[nj], 32);
        float inv = 1.f / lsum[nj];
        unsigned short* ob = h2T + ((size_t)b * kL + nbase + 16 * nj + ll) * kC + h * 32;
#pragma unroll
        for (int dj = 0; dj < 2; ++dj) {
            *(uint2*)(ob + 16 * dj + 4 * hi) =
                make_uint2(cvt_pk(acc[nj][dj][0] * inv, acc[nj][dj][1] * inv),
                           cvt_pk(acc[nj][dj][2] * inv, acc[nj][dj][3] * inv));
        }
    }
}

// ---------------------------------------------------------------------------
// OUT GEMM, W-in-registers. Block: o-tile 64 (wave=16), n-tile 64.
// out[o][n] = sum_c Wout[o][c] h2T[n][c] + bias + x, fp32 out.
// ---------------------------------------------------------------------------
__global__ __launch_bounds__(256) void out_gemm(const unsigned short* __restrict__ Wb,
                                                const unsigned short* __restrict__ h2T,
                                                const float* __restrict__ outb,
                                                const float* __restrict__ x,
                                                float* __restrict__ out) {
    int t = threadIdx.x, wv = t >> 6, ll = t & 15, lg = (t >> 4) & 3;
    int n0 = blockIdx.x * 64, o0 = blockIdx.y * 64, b = blockIdx.z;
    int obase = o0 + wv * 16;
    const unsigned short* hb = h2T + (size_t)b * kL * kC;

    bf16x8 wf[8];
#pragma unroll
    for (int k = 0; k < 8; ++k)
        wf[k] = *(const bf16x8*)(Wb + (size_t)(obase + ll) * 256 + 32 * k + 8 * lg);
    float bias[4];
#pragma unroll
    for (int r = 0; r < 4; ++r) bias[r] = outb[obase + 4 * lg + r];

    for (int np = 0; np < 2; ++np) {
        f32x4 acc0 = {}, acc1 = {};
        int nA = n0 + np * 32 + ll, nB = nA + 16;
#pragma unroll
        for (int k = 0; k < 8; ++k) {
            bf16x8 h0 = *(const bf16x8*)(hb + (size_t)nA * 256 + 32 * k + 8 * lg);
            bf16x8 h1 = *(const bf16x8*)(hb + (size_t)nB * 256 + 32 * k + 8 * lg);
            acc0 = mfma16(wf[k], h0, acc0);
            acc1 = mfma16(wf[k], h1, acc1);
        }
#pragma unroll
        for (int r = 0; r < 4; ++r) {
            size_t row = (size_t)b * kC + obase + 4 * lg + r;
            out[row * kL + nA] = acc0[r] + bias[r] + x[row * kL + nA];
            out[row * kL + nB] = acc1[r] + bias[r] + x[row * kL + nB];
        }
    }
}

// ---------------------------------------------------------------------------
extern "C" void kernel_launch(void* const* d_in, const int* in_sizes, int n_in,
                              void* d_out, int out_size, void* d_ws, size_t ws_size,
                              hipStream_t stream) {
    const float* x     = (const float*)d_in[0];
    const float* gn_w  = (const float*)d_in[1];
    const float* gn_b  = (const float*)d_in[2];
    const float* qkv_w = (const float*)d_in[3];
    const float* qkv_b = (const float*)d_in[4];
    const float* out_w = (const float*)d_in[5];
    const float* out_b = (const float*)d_in[6];
    float* out = (float*)d_out;

    char* ws = (char*)d_ws;
    const size_t MB = 1024 * 1024;
    unsigned short* hT   = (unsigned short*)(ws);             // 0-4 MB
    unsigned short* qT   = (unsigned short*)(ws + 4  * MB);   // 4-8 MB
    unsigned short* kT   = (unsigned short*)(ws + 8  * MB);   // 8-12 MB
    unsigned short* vbuf = (unsigned short*)(ws + 12 * MB);   // 12-16 MB
    unsigned short* h2T  = (unsigned short*)(ws + 16 * MB);   // 16-20 MB
    unsigned short* wqkv = (unsigned short*)(ws + 20 * MB);   // 20-20.375 MB
    unsigned short* wout = (unsigned short*)(ws + 20 * MB + 512 * 1024);

    gncvt_kernel<<<dim3(384), 256, 0, stream>>>(x, gn_w, gn_b, hT, qkv_w, out_w, wqkv, wout);
    qkv_gemm<<<dim3(16, 12, kB), 256, 0, stream>>>(wqkv, hT, qkv_b, qT, kT, vbuf);
    attn_kernel<<<dim3(512), 256, 0, stream>>>(qT, kT, vbuf, h2T);
    out_gemm<<<dim3(32, 4, kB), 256, 0, stream>>>(wout, h2T, out_b, x, out);
}